// Round 8
// baseline (180.103 us; speedup 1.0000x reference)
//
#include <hip/hip_runtime.h>

// ---------------------------------------------------------------------------
// CausalSelfAttentionHead: B=8, S=2048, E=1024, H=64, scale = 1/H (NOT 1/sqrt)
// r7 lesson: B fragment-layout fixed B's txn scatter (64.6->43us, proportional
// to txn count). Remaining: A-path 16-row/instr scatter + wave-private serial
// chain. r8: block-cooperative coalesced A staging into dbuf LDS (m97-style,
// 1 barrier/chunk), fragment ds_read + fp32->bf16 cvt in regs, B unchanged.
// k0 prep_w : W fp32 -> WtF bf16 fragment order [kk][ntl][ks][lane]x8
// k1 proj   : grid 512 = 256 m-tiles(64) x 2 n-halves(96); block 256 = 4 waves
//             wave = 32 rows x 48 cols. A: coalesced global -> LDS dbuf.
// k2 swz    : K,V -> fragment order (once)
// k3 attn   : r7 verbatim (proven): M=32 strips paired, 2-slot p_lds pipe.
// ws: WtF @0, qw @0x60000, kw @0x260000, vT @0x460000,
//     kswz @0x660000, vswz @0x860000  (10.4 MB total)
// ---------------------------------------------------------------------------

typedef __bf16 bf16;
typedef bf16 bf16x8 __attribute__((ext_vector_type(8)));
typedef bf16 bf16x4 __attribute__((ext_vector_type(4)));
typedef float v4f __attribute__((ext_vector_type(4)));

#define MFMA_BF16 __builtin_amdgcn_mfma_f32_16x16x32_bf16

constexpr int SEQ = 2048, EDIM = 1024, HDIM = 64;
constexpr float SCALE_L2E = 1.4426950408889634f / 64.0f;  // log2(e)/head_size

// ---------------- kernel 0: weights -> fragment layout ---------------------
__global__ __launch_bounds__(256) void prep_w_kernel(
    const float* __restrict__ Wq, const float* __restrict__ Wk,
    const float* __restrict__ Wv, bf16* __restrict__ WtF) {
  const int tg = blockIdx.x * 256 + threadIdx.x;  // 24576 = 384 frags x 64
  const int lane = tg & 63, f = tg >> 6;
  const int kk = f / 24, rem = f % 24, ntl = rem >> 1, ks = rem & 1;
  const int q = lane >> 4, l16 = lane & 15;
  const float* src = (ntl < 4) ? Wq : ((ntl < 8) ? Wk : Wv);
  const int n = (ntl & 3) * 16 + l16;
  const int k0 = kk * 64 + 32 * ks + 8 * q;
  bf16x8 v;
#pragma unroll
  for (int j = 0; j < 8; ++j) v[j] = (bf16)src[(k0 + j) * 64 + n];
  *reinterpret_cast<bf16x8*>(WtF + (size_t)tg * 8) = v;
}

// ---------------- kernel 1: block-cooperative QKV projection ---------------
// grid 512: mb = blk>>1 (64-row tile), nh = blk&1 (96-col half).
// block 256 = 4 waves: wave (mi=w&1, nj=w>>1) = rows 32mi..+31, n-tiles
// nb..nb+2 where nb = 6*nh + 3*nj.
__global__ __launch_bounds__(256, 2) void proj_kernel(
    const float* __restrict__ x, const bf16* __restrict__ WtF,
    bf16* __restrict__ qw, bf16* __restrict__ kw, bf16* __restrict__ vT) {
  __shared__ __align__(16) float As[2][64][68];  // +4 pad: 2-way conflicts only

  const int t = threadIdx.x;
  const int w = t >> 6, lane = t & 63, quad = lane >> 4, l16 = lane & 15;
  const int mi = w & 1, nj = w >> 1;
  const int mb = blockIdx.x >> 1, nh = blockIdx.x & 1;
  const int m0 = mb * 64;
  const int nb = 6 * nh + 3 * nj;  // wave's first global n-tile

  // A staging: thread t covers row t>>2, 16 floats at col (t&3)*16 (coalesced:
  // each wave-instr = 16 rows x 64B, every line fully consumed once).
  const int srow = t >> 2, scf = (t & 3) * 16;
  const float* xs = x + (size_t)(m0 + srow) * EDIM + scf;

  v4f acc[2][3] = {};
  float4 sReg[2][4];   // [slot = chunk&1][4 float4] A staging regs, 3-deep issue
  bf16x8 bReg[2][6];   // [slot = chunk&1][2*nt+ks]  B fragments, 2-deep

  auto loadS = [&](int kk, int s) {
    const float* p = xs + kk * 64;
#pragma unroll
    for (int i = 0; i < 4; ++i)
      sReg[s][i] = *reinterpret_cast<const float4*>(p + 4 * i);
  };
  auto commitS = [&](int s, int buf) {
#pragma unroll
    for (int i = 0; i < 4; ++i)
      *reinterpret_cast<float4*>(&As[buf][srow][scf + 4 * i]) = sReg[s][i];
  };
  auto loadB = [&](int kk, int s) {
#pragma unroll
    for (int nt = 0; nt < 3; ++nt)
#pragma unroll
      for (int ks = 0; ks < 2; ++ks)
        bReg[s][2 * nt + ks] = *reinterpret_cast<const bf16x8*>(
            WtF + (size_t)((kk * 24 + (nb + nt) * 2 + ks) * 64 + lane) * 8);
  };

  loadS(0, 0);
  loadB(0, 0);
  commitS(0, 0);       // chunk 0 -> As[0] (waits its own loads only)
  loadS(1, 1);
  loadS(2, 0);
  loadB(1, 1);
  __syncthreads();     // As[0] visible

#pragma unroll 2
  for (int kk = 0; kk < 16; ++kk) {
    const int buf = kk & 1;
    // A fragments: ds_read 32B fp32 + cvt -> bf16 (2-way bank alias = free)
    bf16x8 af[2][2];
#pragma unroll
    for (int m2 = 0; m2 < 2; ++m2)
#pragma unroll
      for (int ks = 0; ks < 2; ++ks) {
        const float* ap =
            &As[buf][32 * mi + 16 * m2 + l16][32 * ks + 8 * quad];
#pragma unroll
        for (int j = 0; j < 8; ++j) af[m2][ks][j] = (bf16)ap[j];
      }
    if (kk + 1 < 16) commitS((kk + 1) & 1, buf ^ 1);  // stage chunk kk+1
    if (kk + 3 < 16) loadS(kk + 3, (kk + 3) & 1);     // 3-deep A prefetch
#pragma unroll
    for (int m2 = 0; m2 < 2; ++m2)
#pragma unroll
      for (int nt = 0; nt < 3; ++nt)
#pragma unroll
        for (int ks = 0; ks < 2; ++ks)
          acc[m2][nt] =
              MFMA_BF16(af[m2][ks], bReg[buf][2 * nt + ks], acc[m2][nt], 0, 0, 0);
    if (kk + 2 < 16) loadB(kk + 2, buf);  // after last use of bReg[buf]
    __syncthreads();  // reads of As[buf] done; As[buf^1] commits visible
  }

  // epilogue: C/D row = 4*quad+r (token), col = l16 (n within 16-tile)
#pragma unroll
  for (int m2 = 0; m2 < 2; ++m2) {
    const int token0 = m0 + 32 * mi + 16 * m2 + 4 * quad;
#pragma unroll
    for (int nt = 0; nt < 3; ++nt) {
      const int tl = nb + nt;  // global n-tile 0..11 (wave-uniform)
      if (tl < 4) {
        const int n = 16 * tl + l16;
#pragma unroll
        for (int r = 0; r < 4; ++r)
          qw[(size_t)(token0 + r) * HDIM + n] = (bf16)acc[m2][nt][r];
      } else if (tl < 8) {
        const int n = 16 * (tl - 4) + l16;
#pragma unroll
        for (int r = 0; r < 4; ++r)
          kw[(size_t)(token0 + r) * HDIM + n] = (bf16)acc[m2][nt][r];
      } else {
        const int hrow = 16 * (tl - 8) + l16;
        const int b = token0 >> 11, s0 = token0 & 2047;
        bf16x4 pk = {(bf16)acc[m2][nt][0], (bf16)acc[m2][nt][1],
                     (bf16)acc[m2][nt][2], (bf16)acc[m2][nt][3]};
        *reinterpret_cast<bf16x4*>(
            vT + ((size_t)(b * 64 + hrow)) * SEQ + s0) = pk;
      }
    }
  }
}

// ---------------- kernel 2: K,V -> fragment layout -------------------------
__global__ __launch_bounds__(256) void swz_kernel(
    const bf16* __restrict__ kw, const bf16* __restrict__ vT,
    bf16* __restrict__ kswz, bf16* __restrict__ vswz) {
  const int batch = blockIdx.x & 7;
  const int jt = blockIdx.x >> 3;  // 0..31
  const int t = threadIdx.x, lane = t & 63;
  const int q = lane >> 4, l16 = lane & 15;
  const bf16* kB = kw + (size_t)batch * SEQ * HDIM;
  const bf16* vB = vT + (size_t)batch * HDIM * SEQ;
  bf16* kS = kswz + (size_t)batch * 131072;
  bf16* vS = vswz + (size_t)batch * 131072;
#pragma unroll
  for (int rep = 0; rep < 4; ++rep) {
    const int fi = rep * 4 + (t >> 6);  // 0..15
    const int nt = (fi & 7) >> 1, h = fi & 1;
    bf16x8 v;
    if (fi < 8)
      v = *reinterpret_cast<const bf16x8*>(
          kB + (size_t)(64 * jt + 16 * nt + l16) * HDIM + 32 * h + 8 * q);
    else
      v = *reinterpret_cast<const bf16x8*>(
          vB + (size_t)(16 * nt + l16) * SEQ + 64 * jt + 32 * h + 8 * q);
    bf16* dst = (fi < 8) ? kS : vS;
    *reinterpret_cast<bf16x8*>(
        dst + (size_t)((jt * 8 + nt * 2 + h) * 64 + lane) * 8) = v;
  }
}

// ---------------- kernel 3: pipelined flash attention (M=32) ---------------
__global__ __launch_bounds__(256) void attn_kernel(
    const bf16* __restrict__ qw, const bf16* __restrict__ kswz,
    const bf16* __restrict__ vswz, float* __restrict__ out) {
  const int batch = blockIdx.x & 7;
  const int pi = blockIdx.x >> 3;  // 0..31
  const int w = threadIdx.x >> 6;
  const int lane = threadIdx.x & 63;
  const int quad = lane >> 4, l16 = lane & 15;

  __shared__ __align__(16) bf16 p_lds[4][2][32][68];
  __shared__ __align__(16) float o_lds[3][32][68];
  __shared__ float l_lds[3][32];

  const bf16* qB = qw + (size_t)batch * SEQ * HDIM;
  const bf16* kS = kswz + (size_t)batch * 131072;
  const bf16* vS = vswz + (size_t)batch * 131072;

  for (int sp = 0; sp < 2; ++sp) {
    const int j = sp ? (63 - pi) : pi;  // strip: rows 32j..32j+31
    const int q0 = 32 * j;
    const int T64 = (j + 2) >> 1;
    const int nw = (T64 > w) ? (((T64 - 1 - w) >> 2) + 1) : 0;

    bf16x8 aq[2][2];
#pragma unroll
    for (int mi = 0; mi < 2; ++mi)
#pragma unroll
      for (int kf = 0; kf < 2; ++kf)
        aq[mi][kf] = *reinterpret_cast<const bf16x8*>(
            qB + (size_t)(q0 + 16 * mi + l16) * HDIM + 32 * kf + 8 * quad);

    v4f accO[2][4] = {};
    float l_part[2][4] = {{0.f, 0.f, 0.f, 0.f}, {0.f, 0.f, 0.f, 0.f}};
    bf16x8 kfr[4][2];

    auto loadK = [&](int jt) {
#pragma unroll
      for (int nt = 0; nt < 4; ++nt)
#pragma unroll
        for (int kf = 0; kf < 2; ++kf)
          kfr[nt][kf] = *reinterpret_cast<const bf16x8*>(
              kS + (size_t)((jt * 8 + nt * 2 + kf) * 64 + lane) * 8);
    };
    auto qk_exp_stage = [&](int jt, int slot) {
      v4f s[2][4] = {};
#pragma unroll
      for (int mi = 0; mi < 2; ++mi)
#pragma unroll
        for (int nt = 0; nt < 4; ++nt) {
          s[mi][nt] = MFMA_BF16(aq[mi][0], kfr[nt][0], s[mi][nt], 0, 0, 0);
          s[mi][nt] = MFMA_BF16(aq[mi][1], kfr[nt][1], s[mi][nt], 0, 0, 0);
        }
      const bool last = (jt == T64 - 1);
#pragma unroll
      for (int mi = 0; mi < 2; ++mi)
#pragma unroll
        for (int nt = 0; nt < 4; ++nt)
#pragma unroll
          for (int r = 0; r < 4; ++r) {
            float p = __builtin_amdgcn_exp2f(s[mi][nt][r] * SCALE_L2E);
            if (last &&
                (64 * jt + 16 * nt + l16 > q0 + 16 * mi + 4 * quad + r))
              p = 0.f;
            l_part[mi][r] += p;
            p_lds[w][slot][16 * mi + 4 * quad + r][16 * nt + l16] = (bf16)p;
          }
    };

    if (nw > 0) {
      loadK(w);
      qk_exp_stage(w, 0);
    }
    for (int i = 0; i < nw; ++i) {
      const int jt = w + 4 * i;
      if (i + 1 < nw) loadK(jt + 4);
      bf16x8 vfr[4][2];
#pragma unroll
      for (int nt = 0; nt < 4; ++nt)
#pragma unroll
        for (int kc = 0; kc < 2; ++kc)
          vfr[nt][kc] = *reinterpret_cast<const bf16x8*>(
              vS + (size_t)((jt * 8 + nt * 2 + kc) * 64 + lane) * 8);
      asm volatile("s_waitcnt lgkmcnt(0)" ::: "memory");
      bf16x8 pa[2][2];
#pragma unroll
      for (int mi = 0; mi < 2; ++mi)
#pragma unroll
        for (int kc = 0; kc < 2; ++kc)
          pa[mi][kc] = *reinterpret_cast<const bf16x8*>(
              &p_lds[w][i & 1][16 * mi + l16][32 * kc + 8 * quad]);
      if (i + 1 < nw) qk_exp_stage(jt + 4, (i + 1) & 1);
#pragma unroll
      for (int mi = 0; mi < 2; ++mi)
#pragma unroll
        for (int nt = 0; nt < 4; ++nt) {
          accO[mi][nt] = MFMA_BF16(pa[mi][0], vfr[nt][0], accO[mi][nt], 0, 0, 0);
          accO[mi][nt] = MFMA_BF16(pa[mi][1], vfr[nt][1], accO[mi][nt], 0, 0, 0);
        }
    }

#pragma unroll
    for (int mi = 0; mi < 2; ++mi)
#pragma unroll
      for (int r = 0; r < 4; ++r) {
        float s = l_part[mi][r];
        s += __shfl_xor(s, 1, 16);
        s += __shfl_xor(s, 2, 16);
        s += __shfl_xor(s, 4, 16);
        s += __shfl_xor(s, 8, 16);
        l_part[mi][r] = s;
      }

    __syncthreads();
    if (w > 0) {
#pragma unroll
      for (int mi = 0; mi < 2; ++mi)
#pragma unroll
        for (int nt = 0; nt < 4; ++nt)
#pragma unroll
          for (int r = 0; r < 4; ++r)
            o_lds[w - 1][16 * mi + 4 * quad + r][16 * nt + l16] =
                accO[mi][nt][r];
      if (l16 == 0) {
#pragma unroll
        for (int mi = 0; mi < 2; ++mi)
#pragma unroll
          for (int r = 0; r < 4; ++r)
            l_lds[w - 1][16 * mi + 4 * quad + r] = l_part[mi][r];
      }
    }
    __syncthreads();
    if (w == 0) {
#pragma unroll
      for (int mi = 0; mi < 2; ++mi)
#pragma unroll
        for (int r = 0; r < 4; ++r) {
          const int row = 16 * mi + 4 * quad + r;
          float lt = l_part[mi][r] + l_lds[0][row] + l_lds[1][row] +
                     l_lds[2][row];
          float inv = 1.0f / lt;
          float* op = out + ((size_t)batch * SEQ + q0 + row) * HDIM;
#pragma unroll
          for (int nt = 0; nt < 4; ++nt)
            op[16 * nt + l16] =
                (accO[mi][nt][r] + o_lds[0][row][16 * nt + l16] +
                 o_lds[1][row][16 * nt + l16] +
                 o_lds[2][row][16 * nt + l16]) *
                inv;
        }
    }
  }
}

// ---------------- launcher -------------------------------------------------
extern "C" void kernel_launch(void* const* d_in, const int* in_sizes, int n_in,
                              void* d_out, int out_size, void* d_ws,
                              size_t ws_size, hipStream_t stream) {
  const float* x = (const float*)d_in[0];
  const float* Wq = (const float*)d_in[1];
  const float* Wk = (const float*)d_in[2];
  const float* Wv = (const float*)d_in[3];

  char* ws = (char*)d_ws;
  bf16* WtF = (bf16*)(ws);
  bf16* qw = (bf16*)(ws + 0x60000);
  bf16* kw = (bf16*)(ws + 0x260000);
  bf16* vT = (bf16*)(ws + 0x460000);
  bf16* kswz = (bf16*)(ws + 0x660000);
  bf16* vswz = (bf16*)(ws + 0x860000);

  prep_w_kernel<<<96, 256, 0, stream>>>(Wq, Wk, Wv, WtF);
  proj_kernel<<<512, 256, 0, stream>>>(x, WtF, qw, kw, vT);
  swz_kernel<<<256, 256, 0, stream>>>(kw, vT, kswz, vswz);
  attn_kernel<<<256, 256, 0, stream>>>(qw, kswz, vswz, (float*)d_out);
}